// Round 5
// baseline (130.761 us; speedup 1.0000x reference)
//
#include <hip/hip_runtime.h>

// hex pooling: out[i][c] = max_{k<7} x[hex_idx[i][k]][c]
// 256-thread blocks, 2 output rows per block (waves 0,1 -> row A; waves 2,3 ->
// row B; idx addresses wave-uniform -> scalar s_load). Nontemporal stores keep
// the 21 MB output stream from evicting gatherable x lines in L2.

typedef float v4f __attribute__((ext_vector_type(4)));

__global__ __launch_bounds__(256) void hex_pool_kernel(
        const float* __restrict__ x,
        const int* __restrict__ idx,
        float* __restrict__ out,
        int C4 /* C/4 = 128 */) {
    const int row = blockIdx.x * 2 + (threadIdx.x >> 7);  // wave-uniform
    const int col = threadIdx.x & 127;                    // 0..127, one float4

    const int* __restrict__ ib = idx + (long long)row * 7;
    int r0 = ib[0], r1 = ib[1], r2 = ib[2], r3 = ib[3];
    int r4 = ib[4], r5 = ib[5], r6 = ib[6];

    const v4f* __restrict__ x4 = reinterpret_cast<const v4f*>(x);

    v4f v0 = x4[(long long)r0 * C4 + col];
    v4f v1 = x4[(long long)r1 * C4 + col];
    v4f v2 = x4[(long long)r2 * C4 + col];
    v4f v3 = x4[(long long)r3 * C4 + col];
    v4f v4 = x4[(long long)r4 * C4 + col];
    v4f v5 = x4[(long long)r5 * C4 + col];
    v4f v6 = x4[(long long)r6 * C4 + col];

    v4f m;
#pragma unroll
    for (int j = 0; j < 4; ++j) {
        m[j] = fmaxf(fmaxf(fmaxf(v0[j], v1[j]), fmaxf(v2[j], v3[j])),
                     fmaxf(fmaxf(v4[j], v5[j]), v6[j]));
    }

    v4f* __restrict__ o = reinterpret_cast<v4f*>(out) +
                          (long long)row * C4 + col;
    __builtin_nontemporal_store(m, o);
}

extern "C" void kernel_launch(void* const* d_in, const int* in_sizes, int n_in,
                              void* d_out, int out_size, void* d_ws, size_t ws_size,
                              hipStream_t stream) {
    const float* x = (const float*)d_in[0];
    const int* idx = (const int*)d_in[1];
    float* out = (float*)d_out;

    const int K = 7;
    const int n = in_sizes[1] / K;        // 40962
    const int C = in_sizes[0] / n;        // 512
    const int C4 = C / 4;                 // 128
    const int L = out_size / C;           // 10242 (even)

    int grid = (L + 1) / 2;               // 2 rows per block
    hex_pool_kernel<<<grid, 256, 0, stream>>>(x, idx, out, C4);
}